// Round 1
// baseline (185.011 us; speedup 1.0000x reference)
//
#include <hip/hip_runtime.h>

// Layout constants for activation (32, 16, 224, 224) fp32
#define HW      224
#define PLANE   50176            // 224*224
#define NSTRIDE 802816           // 16*PLANE

// Grid partition, dispatched SLOWEST-FIRST to avoid a heavy tail:
// D: ch 12..15 (3x3) register scheme  : 713 blocks  (182400 units, 3rows x 12cols each)
// C: ch  8..11 (4x4) one block/thr    : 1568 blocks
// B: ch  4..7  (2x2) one 2x4 region/th: 3136 blocks
// A: ch  0..3  copy/relu, 2 float4/thr: 3136 blocks
constexpr int D_END    = 713;
constexpr int DC_END   = D_END + 1568;    // 2281
constexpr int DCB_END  = DC_END + 3136;   // 5417
constexpr int TOTAL_BLOCKS = DCB_END + 3136;  // 8553

__global__ __launch_bounds__(256) void blockrelu_kernel(
    const float* __restrict__ in, float* __restrict__ out) {
  const int bid = blockIdx.x;
  const int t = threadIdx.x;

  if (bid < D_END) {
    // 3x3 blocks, register-only: thread owns 3 rows x 12 cols = four 3x3 blocks.
    // 9 independent float4 loads in flight; no LDS, no barriers.
    // Units: 128 planes x 75 row-triples x 19 col-units = 182400.
    //   cu 0..17: cols 12*cu .. 12*cu+11 (3 float4/row, 4 blocks)
    //   cu 18   : cols 216..223          (2 float4/row, 3 blocks, last is 2 wide)
    //   br 0..73: rows 3*br .. 3*br+2 ;  br 74: rows 222..223 (2 rows)
    int u = bid * 256 + t;
    if (u < 182400) {
      int p   = u / 1425;            // plane 0..127
      int rem = u - p * 1425;
      int br  = rem / 19;            // 0..74
      int cu  = rem - br * 19;       // 0..18
      int n = p >> 2;
      int c = 12 + (p & 3);
      const bool full = (cu < 18);   // 3 float4s per row?
      const bool r3   = (br < 74);   // 3 rows?
      long base = (long)n * NSTRIDE + (long)c * PLANE + (long)(3 * br) * HW + 12 * cu;

      const float4 z4 = make_float4(0.f, 0.f, 0.f, 0.f);
      float4 x00, x01, x02 = z4;
      float4 x10, x11, x12 = z4;
      float4 x20 = z4, x21 = z4, x22 = z4;
      x00 = *(const float4*)(in + base);
      x01 = *(const float4*)(in + base + 4);
      if (full) x02 = *(const float4*)(in + base + 8);
      x10 = *(const float4*)(in + base + HW);
      x11 = *(const float4*)(in + base + HW + 4);
      if (full) x12 = *(const float4*)(in + base + HW + 8);
      if (r3) {
        x20 = *(const float4*)(in + base + 2 * HW);
        x21 = *(const float4*)(in + base + 2 * HW + 4);
        if (full) x22 = *(const float4*)(in + base + 2 * HW + 8);
      }

      // Block sums in exact row-major order (rows 0..2, cols ascending).
      // Missing rows/cols contribute 0.f; only zero-sign can differ, and the
      // mask test (s >= 0) is insensitive to zero sign.
      float s0, s1, s2, s3;
      s0 = x00.x; s0 += x00.y; s0 += x00.z;
      s0 += x10.x; s0 += x10.y; s0 += x10.z;
      s0 += x20.x; s0 += x20.y; s0 += x20.z;

      s1 = x00.w; s1 += x01.x; s1 += x01.y;
      s1 += x10.w; s1 += x11.x; s1 += x11.y;
      s1 += x20.w; s1 += x21.x; s1 += x21.y;

      s2 = x01.z; s2 += x01.w; s2 += x02.x;
      s2 += x11.z; s2 += x11.w; s2 += x12.x;
      s2 += x21.z; s2 += x21.w; s2 += x22.x;

      s3 = x02.y; s3 += x02.z; s3 += x02.w;
      s3 += x12.y; s3 += x12.z; s3 += x12.w;
      s3 += x22.y; s3 += x22.z; s3 += x22.w;

      if (s0 < 0.f) { x00.x = x00.y = x00.z = 0.f;
                      x10.x = x10.y = x10.z = 0.f;
                      x20.x = x20.y = x20.z = 0.f; }
      if (s1 < 0.f) { x00.w = x01.x = x01.y = 0.f;
                      x10.w = x11.x = x11.y = 0.f;
                      x20.w = x21.x = x21.y = 0.f; }
      if (s2 < 0.f) { x01.z = x01.w = x02.x = 0.f;
                      x11.z = x11.w = x12.x = 0.f;
                      x21.z = x21.w = x22.x = 0.f; }
      if (s3 < 0.f) { x02.y = x02.z = x02.w = 0.f;
                      x12.y = x12.z = x12.w = 0.f;
                      x22.y = x22.z = x22.w = 0.f; }

      *(float4*)(out + base) = x00;
      *(float4*)(out + base + 4) = x01;
      if (full) *(float4*)(out + base + 8) = x02;
      *(float4*)(out + base + HW) = x10;
      *(float4*)(out + base + HW + 4) = x11;
      if (full) *(float4*)(out + base + HW + 8) = x12;
      if (r3) {
        *(float4*)(out + base + 2 * HW) = x20;
        *(float4*)(out + base + 2 * HW + 4) = x21;
        if (full) *(float4*)(out + base + 2 * HW + 8) = x22;
      }
    }
  } else if (bid < DC_END) {
    // 4x4 blocks: one block per thread
    int u = (bid - D_END) * 256 + t;
    int n = u / 12544;
    int v2 = u - n * 12544;
    int c = 8 + v2 / 3136;
    int w2 = v2 % 3136;
    int by = w2 / 56;
    int bx = w2 - by * 56;
    long base = (long)n * NSTRIDE + (long)c * PLANE + (long)(4 * by) * HW + 4 * bx;
    float4 r0 = *(const float4*)(in + base);
    float4 r1 = *(const float4*)(in + base + HW);
    float4 r2 = *(const float4*)(in + base + 2 * HW);
    float4 r3 = *(const float4*)(in + base + 3 * HW);
    float s = r0.x; s += r0.y; s += r0.z; s += r0.w;
    s += r1.x; s += r1.y; s += r1.z; s += r1.w;
    s += r2.x; s += r2.y; s += r2.z; s += r2.w;
    s += r3.x; s += r3.y; s += r3.z; s += r3.w;
    if (s < 0.f) {
      r0 = make_float4(0.f, 0.f, 0.f, 0.f);
      r1 = r0; r2 = r0; r3 = r0;
    }
    *(float4*)(out + base) = r0;
    *(float4*)(out + base + HW) = r1;
    *(float4*)(out + base + 2 * HW) = r2;
    *(float4*)(out + base + 3 * HW) = r3;
  } else if (bid < DCB_END) {
    // 2x2 blocks: thread handles a 2-row x 4-col region (two blocks)
    int u = (bid - DC_END) * 256 + t;
    int n = u / 25088;
    int v2 = u - n * 25088;
    int c = 4 + v2 / 6272;
    int w2 = v2 % 6272;
    int brow = w2 / 56;
    int rcol = w2 - brow * 56;
    long base = (long)n * NSTRIDE + (long)c * PLANE + (long)(2 * brow) * HW + 4 * rcol;
    float4 a = *(const float4*)(in + base);
    float4 b = *(const float4*)(in + base + HW);
    float s0 = ((a.x + a.y) + b.x) + b.y;   // row-major order (matches XLA exactly)
    float s1 = ((a.z + a.w) + b.z) + b.w;
    if (s0 < 0.f) { a.x = 0.f; a.y = 0.f; b.x = 0.f; b.y = 0.f; }
    if (s1 < 0.f) { a.z = 0.f; a.w = 0.f; b.z = 0.f; b.w = 0.f; }
    *(float4*)(out + base) = a;
    *(float4*)(out + base + HW) = b;
  } else {
    // Channels 0..3: copy (ch 0-1) or elementwise ReLU (ch 2-3).
    // Two independent float4s per thread for MLP.
    int tid1 = (bid - DCB_END) * 512 + t;   // float4 index; 50176 float4s per n
    int tid2 = tid1 + 256;
    int n1 = tid1 / PLANE;
    int r1 = tid1 - n1 * PLANE;
    int c1 = r1 / 12544;
    long off1 = (long)n1 * NSTRIDE + (long)r1 * 4;
    int n2 = tid2 / PLANE;
    int r2 = tid2 - n2 * PLANE;
    int c2 = r2 / 12544;
    long off2 = (long)n2 * NSTRIDE + (long)r2 * 4;
    float4 v1 = *(const float4*)(in + off1);
    float4 v2 = *(const float4*)(in + off2);
    if (c1 >= 2) {
      v1.x = (v1.x >= 0.f) ? v1.x : 0.f;
      v1.y = (v1.y >= 0.f) ? v1.y : 0.f;
      v1.z = (v1.z >= 0.f) ? v1.z : 0.f;
      v1.w = (v1.w >= 0.f) ? v1.w : 0.f;
    }
    if (c2 >= 2) {
      v2.x = (v2.x >= 0.f) ? v2.x : 0.f;
      v2.y = (v2.y >= 0.f) ? v2.y : 0.f;
      v2.z = (v2.z >= 0.f) ? v2.z : 0.f;
      v2.w = (v2.w >= 0.f) ? v2.w : 0.f;
    }
    *(float4*)(out + off1) = v1;
    *(float4*)(out + off2) = v2;
  }
}

extern "C" void kernel_launch(void* const* d_in, const int* in_sizes, int n_in,
                              void* d_out, int out_size, void* d_ws, size_t ws_size,
                              hipStream_t stream) {
  const float* act = (const float*)d_in[0];
  float* out = (float*)d_out;
  blockrelu_kernel<<<TOTAL_BLOCKS, 256, 0, stream>>>(act, out);
}